// Round 1
// baseline (401.149 us; speedup 1.0000x reference)
//
#include <hip/hip_runtime.h>
#include <hip/hip_bf16.h>

// mean_aggregator: out[b,:] = mean over s of emb[neighbors[b,s], :]
// B=50000, S=32, D=128. neighbors int32, emb float32, out float32.
//
// Layout: 32 lanes per output row, each lane owns one float4 (4 dims).
// 32 lanes x 16B = 512B = one full embedding row -> perfectly coalesced
// gather per neighbor. 8 rows per 256-thread block. Full unroll over S
// so the compiler issues many independent global loads (deep MLP to hide
// ~900-cycle HBM-miss latency on the random gather).

#define AGG_BATCH 50000
#define AGG_S 32
#define AGG_D4 32   // 128 dims / 4 = 32 float4 chunks
#define AGG_ROWS_PER_BLOCK 8

__global__ __launch_bounds__(256) void mean_aggregator_49795850830175_kernel(
    const int* __restrict__ neighbors,
    const float4* __restrict__ emb,
    float4* __restrict__ out) {
  const int tid = threadIdx.x;
  const int chunk = tid & 31;                       // float4 chunk within row
  const int row = blockIdx.x * AGG_ROWS_PER_BLOCK + (tid >> 5);
  if (row >= AGG_BATCH) return;

  const int* __restrict__ nb = neighbors + (size_t)row * AGG_S;

  float4 acc = make_float4(0.f, 0.f, 0.f, 0.f);
#pragma unroll
  for (int s = 0; s < AGG_S; ++s) {
    const int idx = nb[s];
    const float4 v = emb[(size_t)idx * AGG_D4 + chunk];
    acc.x += v.x;
    acc.y += v.y;
    acc.z += v.z;
    acc.w += v.w;
  }
  const float inv = 1.0f / (float)AGG_S;
  acc.x *= inv; acc.y *= inv; acc.z *= inv; acc.w *= inv;
  out[(size_t)row * AGG_D4 + chunk] = acc;
}

extern "C" void kernel_launch(void* const* d_in, const int* in_sizes, int n_in,
                              void* d_out, int out_size, void* d_ws, size_t ws_size,
                              hipStream_t stream) {
  const int* neighbors = (const int*)d_in[0];        // [B, S] int32
  const float4* emb = (const float4*)d_in[1];        // [N, D] float32 as float4
  float4* out = (float4*)d_out;                      // [B, D] float32 as float4

  const int grid = (AGG_BATCH + AGG_ROWS_PER_BLOCK - 1) / AGG_ROWS_PER_BLOCK;
  mean_aggregator_49795850830175_kernel<<<grid, 256, 0, stream>>>(neighbors, emb, out);
}

// Round 2
// 398.797 us; speedup vs baseline: 1.0059x; 1.0059x over previous
//
#include <hip/hip_runtime.h>
#include <hip/hip_bf16.h>

// mean_aggregator: out[b,:] = mean over s of emb[neighbors[b,s], :]
// B=50000, S=32, D=128. neighbors int32, emb float32, out float32.
//
// R2 design: ONE 64-lane wave per output row. Lane owns a float2 (64 x 8B =
// 512B = one full embedding row). `row` and each neighbor index are forced
// wave-uniform via readfirstlane, so:
//   - neighbor indices load through the SCALAR path (s_load, off the VMEM
//     critical chain),
//   - gather base address math is SALU (s_lshl/s_add), gather is
//     global_load_dwordx2 v, v_laneoff, s[base] with a loop-invariant VGPR
//     offset,
//   - all 32 gathers per row issue back-to-back (32 independent float2
//     in-flight = 64 VGPRs of data) -> ~4x the memory-level parallelism of
//     the R1 version (which was latency-bound: VALUBusy 5%, hbm 35% peak).

#define AGG_BATCH 50000
#define AGG_S 32
#define AGG_D2 64             // 128 dims / 2 = 64 float2 chunks (one per lane)
#define AGG_WAVES_PER_BLOCK 4

__global__ __launch_bounds__(256) void mean_aggregator_49795850830175_kernel(
    const int* __restrict__ neighbors,
    const float2* __restrict__ emb,
    float2* __restrict__ out) {
  const int lane = threadIdx.x & 63;
  int row = blockIdx.x * AGG_WAVES_PER_BLOCK + (threadIdx.x >> 6);
  row = __builtin_amdgcn_readfirstlane(row);   // wave-uniform -> scalar regs

  const int* __restrict__ nb = neighbors + (size_t)row * AGG_S;

  float acc_x = 0.f, acc_y = 0.f;
#pragma unroll
  for (int s = 0; s < AGG_S; ++s) {
    int idx = __builtin_amdgcn_readfirstlane(nb[s]);  // scalar index load
    const float2 v = emb[(size_t)idx * AGG_D2 + lane]; // SGPR base + lane off
    acc_x += v.x;
    acc_y += v.y;
  }

  const float inv = 1.0f / (float)AGG_S;
  float2 r;
  r.x = acc_x * inv;
  r.y = acc_y * inv;
  out[(size_t)row * AGG_D2 + lane] = r;
}

extern "C" void kernel_launch(void* const* d_in, const int* in_sizes, int n_in,
                              void* d_out, int out_size, void* d_ws, size_t ws_size,
                              hipStream_t stream) {
  const int* neighbors = (const int*)d_in[0];        // [B, S] int32
  const float2* emb = (const float2*)d_in[1];        // [N, D] fp32 as float2
  float2* out = (float2*)d_out;                      // [B, D] fp32 as float2

  const int grid = AGG_BATCH / AGG_WAVES_PER_BLOCK;  // 50000 % 4 == 0
  mean_aggregator_49795850830175_kernel<<<grid, 256, 0, stream>>>(neighbors, emb, out);
}